// Round 1
// 348.727 us; speedup vs baseline: 1.1626x; 1.1626x over previous
//
#include <hip/hip_runtime.h>
#include <math.h>

// ---------------------------------------------------------------------------
// GCN layer: out = tanh( scatter_add(adj_vals * h[src] -> dst)
//                        + seq @ w_proj + b_proj + bias ),   h = seq @ w_fc
// N=100000, E=1600000, D=128, fp32.
// R6 -> R7:
//  * aggregate_sorted is gather-BW-bound (402MB FETCH, 3.47TB/s, VALU 22%).
//    h is now stored fp16 (err ~2^-11 rel, h~N(0,1)): halves the E x row
//    gather traffic (819->410MB logical) and halves h's LLC footprint
//    (51->25.6MB) so residency improves too.
//  * aggregate occupancy 4->8 blocks/CU (LDS 17.9KB x8 fits 160KB).
//  * out RMW in aggregate uses non-temporal ld/st (one-shot stream; don't
//    evict h from LLC).
//  * partition/scan/scatter pipeline unchanged.
// ---------------------------------------------------------------------------

typedef __attribute__((ext_vector_type(8))) short short8;
typedef __attribute__((ext_vector_type(4))) float float4v;
typedef __attribute__((ext_vector_type(2))) _Float16 half2v;

#define PG 128          // partition blocks (slices)
#define NBMAX 2048      // max buckets (64 nodes each)

static __device__ __forceinline__ short f2bf(float x) {
    unsigned u = __float_as_uint(x);
    unsigned r = (u + 0x7fffu + ((u >> 16) & 1u)) >> 16;   // RNE
    return (short)r;
}
static __device__ __forceinline__ float bf2f(short h) {
    return __uint_as_float(((unsigned)(unsigned short)h) << 16);
}

// ---------------- W pre-conversion: w[k][c] fp32 -> whi/wlo[c][k] bf16 ------
__global__ __launch_bounds__(256)
void wconv_kernel(const float* __restrict__ w, short* __restrict__ whi,
                  short* __restrict__ wlo) {
    const int i = blockIdx.x * 256 + threadIdx.x;   // 4096 float4s
    const float4 v = ((const float4*)w)[i];
    const int k = i >> 5;
    const int c4 = (i & 31) * 4;
    float xs[4] = {v.x, v.y, v.z, v.w};
    #pragma unroll
    for (int j = 0; j < 4; j++) {
        const short hi = f2bf(xs[j]);
        const short lo = f2bf(xs[j] - bf2f(hi));
        whi[(c4 + j) * 128 + k] = hi;
        wlo[(c4 + j) * 128 + k] = lo;
    }
}

// ---------------- MFMA matmul: out[N x 128] = seq[N x 128] @ w[128 x 128] ---
// A*B ~= Ah*Bh + Ah*Bl + Al*Bh (split bf16, rel err ~1e-5).
// out16 != nullptr -> store fp16 (h path); else fp32 + bias (proj path).
#define KP 136

__global__ __launch_bounds__(256, 2)
void mm_mfma_kernel(const float* __restrict__ seq, const short* __restrict__ whi,
                    const short* __restrict__ wlo,
                    const float* __restrict__ b0p, const float* __restrict__ b1p,
                    float* __restrict__ out, _Float16* __restrict__ out16,
                    int N, int add_bias) {
    __shared__ short wt_hi[128 * KP];
    __shared__ short wt_lo[128 * KP];

    const int tid = threadIdx.x;
    for (int i = tid; i < 2048; i += 256) {
        const int row = i >> 4;
        const int k8  = (i & 15) * 8;
        *(float4*)&wt_hi[row * KP + k8] = ((const float4*)whi)[i];
        *(float4*)&wt_lo[row * KP + k8] = ((const float4*)wlo)[i];
    }
    __syncthreads();

    const int wave = tid >> 6;
    const int lane = tid & 63;
    const int q = lane >> 4;
    const int c = lane & 15;
    const int R = blockIdx.x * 64 + wave * 16;
    const int rowL = (R + c < N) ? (R + c) : (N - 1);

    float4v acc[8];
    #pragma unroll
    for (int ct = 0; ct < 8; ct++) acc[ct] = (float4v){0.f, 0.f, 0.f, 0.f};

    #pragma unroll
    for (int t = 0; t < 4; t++) {
        const int kk = t * 32 + q * 8;
        const float4 a0 = *(const float4*)&seq[(size_t)rowL * 128 + kk];
        const float4 a1 = *(const float4*)&seq[(size_t)rowL * 128 + kk + 4];
        float xs[8] = {a0.x, a0.y, a0.z, a0.w, a1.x, a1.y, a1.z, a1.w};
        union { short s[8]; short8 v; } ahi, alo;
        #pragma unroll
        for (int j = 0; j < 8; j++) {
            const short hi = f2bf(xs[j]);
            ahi.s[j] = hi;
            alo.s[j] = f2bf(xs[j] - bf2f(hi));
        }
        #pragma unroll
        for (int ct = 0; ct < 8; ct++) {
            const int n = ct * 16 + c;
            const short8 bhi = *(const short8*)&wt_hi[n * KP + kk];
            const short8 blo = *(const short8*)&wt_lo[n * KP + kk];
            acc[ct] = __builtin_amdgcn_mfma_f32_16x16x32_bf16(ahi.v, bhi, acc[ct], 0, 0, 0);
            acc[ct] = __builtin_amdgcn_mfma_f32_16x16x32_bf16(ahi.v, blo, acc[ct], 0, 0, 0);
            acc[ct] = __builtin_amdgcn_mfma_f32_16x16x32_bf16(alo.v, bhi, acc[ct], 0, 0, 0);
        }
    }

    if (out16) {
        #pragma unroll
        for (int ct = 0; ct < 8; ct++) {
            const int col = ct * 16 + c;
            #pragma unroll
            for (int r = 0; r < 4; r++) {
                const int row = R + q * 4 + r;
                if (row < N) out16[(size_t)row * 128 + col] = (_Float16)acc[ct][r];
            }
        }
    } else {
        #pragma unroll
        for (int ct = 0; ct < 8; ct++) {
            const int col = ct * 16 + c;
            float badd = 0.f;
            if (add_bias) badd = b0p[col] + b1p[col];
            #pragma unroll
            for (int r = 0; r < 4; r++) {
                const int row = R + q * 4 + r;
                if (row < N) out[(size_t)row * 128 + col] = acc[ct][r] + badd;
            }
        }
    }
}

// ---------------- atomic-free radix partition (bucket = dst>>6) ------------

// Per-slice LDS histogram -> hcnt[b*PG + g] (bucket-major for the scan).
__global__ __launch_bounds__(256)
void phist_kernel(const int* __restrict__ edst, int* __restrict__ hcnt,
                  int E, int S, int NB) {
    __shared__ int cnt[NBMAX];
    const int g = blockIdx.x;
    const int tid = threadIdx.x;
    for (int b = tid; b < NB; b += 256) cnt[b] = 0;
    __syncthreads();
    const int lo = g * S;
    const int hi = (lo + S < E) ? (lo + S) : E;
    for (int i = lo + tid; i < hi; i += 256)
        atomicAdd(&cnt[edst[i] >> 6], 1);
    __syncthreads();
    for (int b = tid; b < NB; b += 256) hcnt[b * PG + g] = cnt[b];
}

// Exclusive scan over L = NB*PG entries. pscan1: per-block (1024 elems)
// exclusive prefix + block sums.
__global__ __launch_bounds__(256)
void pscan1_kernel(const int* __restrict__ in, int* __restrict__ out,
                   int* __restrict__ bsum, int L) {
    __shared__ int s[256];
    const int t = threadIdx.x;
    const int base = blockIdx.x * 1024 + t * 4;
    int v0 = (base + 0 < L) ? in[base + 0] : 0;
    int v1 = (base + 1 < L) ? in[base + 1] : 0;
    int v2 = (base + 2 < L) ? in[base + 2] : 0;
    int v3 = (base + 3 < L) ? in[base + 3] : 0;
    const int mysum = v0 + v1 + v2 + v3;
    s[t] = mysum;
    __syncthreads();
    for (int o = 1; o < 256; o <<= 1) {
        int add = (t >= o) ? s[t - o] : 0;
        __syncthreads();
        s[t] += add;
        __syncthreads();
    }
    const int excl = s[t] - mysum;
    if (base + 0 < L) out[base + 0] = excl;
    if (base + 1 < L) out[base + 1] = excl + v0;
    if (base + 2 < L) out[base + 2] = excl + v0 + v1;
    if (base + 3 < L) out[base + 3] = excl + v0 + v1 + v2;
    if (t == 255) bsum[blockIdx.x] = s[255];
}

// Single block: exclusive scan of nb (<=256) block sums.
__global__ __launch_bounds__(256)
void pscan2_kernel(const int* __restrict__ bsum, int* __restrict__ ebsum, int nb) {
    __shared__ int s[256];
    const int t = threadIdx.x;
    const int v = (t < nb) ? bsum[t] : 0;
    s[t] = v;
    __syncthreads();
    for (int o = 1; o < 256; o <<= 1) {
        int add = (t >= o) ? s[t - o] : 0;
        __syncthreads();
        s[t] += add;
        __syncthreads();
    }
    if (t < nb) ebsum[t] = s[t] - v;
}

// pos[i] += ebsum[block]; also emit bstart[b] = pos[b*PG] and bstart[NB] = E.
__global__ __launch_bounds__(256)
void paddback_kernel(int* __restrict__ pos, const int* __restrict__ ebsum,
                     int* __restrict__ bstart, int L, int NB, int E) {
    const int add = ebsum[blockIdx.x];
    const int base = blockIdx.x * 1024 + threadIdx.x * 4;
    #pragma unroll
    for (int j = 0; j < 4; j++) {
        const int idx = base + j;
        if (idx < L) {
            const int v = pos[idx] + add;
            pos[idx] = v;
            if ((idx & (PG - 1)) == 0) bstart[idx / PG] = v;
        }
    }
    if (blockIdx.x == 0 && threadIdx.x == 0) bstart[NB] = E;
}

// Atomic-free (global) scatter: LDS cursors seeded from pos.
// entry = (src<<6 | dst&63, val) : 8B.
__global__ __launch_bounds__(256)
void pscatter_kernel(const int* __restrict__ esrc, const int* __restrict__ edst,
                     const float* __restrict__ vals, const int* __restrict__ pos,
                     int2* __restrict__ sedge, int E, int S, int NB) {
    __shared__ int cur[NBMAX];
    const int g = blockIdx.x;
    const int tid = threadIdx.x;
    for (int b = tid; b < NB; b += 256) cur[b] = pos[b * PG + g];
    __syncthreads();
    const int lo = g * S;
    const int hi = (lo + S < E) ? (lo + S) : E;
    for (int i = lo + tid; i < hi; i += 256) {
        const int d = edst[i];
        const int p = atomicAdd(&cur[d >> 6], 1);
        sedge[p] = make_int2((esrc[i] << 6) | (d & 63), __float_as_int(vals[i]));
    }
}

// One block (256 thr) per 64-node bucket. Counting-sort edges by node into
// LDS (16KB), then each wave aggregates 16 nodes with REGISTER accumulation:
// coalesced 256B fp16 h-row gathers, fused tanh. out RMW is non-temporal
// (one-shot stream; keep h resident in LLC).
#define CAP 2048

__global__ __launch_bounds__(256, 8)
void aggregate_sorted(const int* __restrict__ bstart, const int2* __restrict__ sedge,
                      const _Float16* __restrict__ h, float* __restrict__ out, int N) {
    __shared__ int2 ebuf[CAP];
    __shared__ int cnt[64], sc[64], off[65], cur[64];
    const int b = blockIdx.x;
    const int tid = threadIdx.x;
    const int beg = bstart[b];
    const int total = bstart[b + 1] - beg;
    const int cl = total < CAP ? total : CAP;     // edges sorted in LDS

    if (tid < 64) cnt[tid] = 0;
    __syncthreads();
    for (int i = tid; i < cl; i += 256)
        atomicAdd(&cnt[sedge[beg + i].x & 63], 1);
    __syncthreads();
    if (tid < 64) sc[tid] = cnt[tid];
    __syncthreads();
    for (int o = 1; o < 64; o <<= 1) {
        int add = (tid < 64 && tid >= o) ? sc[tid - o] : 0;
        __syncthreads();
        if (tid < 64) sc[tid] += add;
        __syncthreads();
    }
    if (tid < 64) { off[tid] = sc[tid] - cnt[tid]; cur[tid] = sc[tid] - cnt[tid]; }
    if (tid == 63) off[64] = sc[63];
    __syncthreads();
    for (int i = tid; i < cl; i += 256) {
        const int2 e = sedge[beg + i];
        const int p = atomicAdd(&cur[e.x & 63], 1);
        ebuf[p] = e;
    }
    __syncthreads();

    const int wave = tid >> 6;
    const int lane = tid & 63;
    const half2v* hp = (const half2v*)h;

    for (int n = wave * 16; n < wave * 16 + 16; n++) {
        const int node = b * 64 + n;
        if (node >= N) break;
        float2 acc = make_float2(0.f, 0.f);
        const int e0 = off[n], e1 = off[n + 1];
        int j = e0;
        for (; j + 4 <= e1; j += 4) {
            const int2 ea = ebuf[j], eb = ebuf[j + 1], ec = ebuf[j + 2], ed = ebuf[j + 3];
            const half2v h0 = hp[(size_t)(ea.x >> 6) * 64 + lane];
            const half2v h1 = hp[(size_t)(eb.x >> 6) * 64 + lane];
            const half2v h2 = hp[(size_t)(ec.x >> 6) * 64 + lane];
            const half2v h3 = hp[(size_t)(ed.x >> 6) * 64 + lane];
            const float v0 = __int_as_float(ea.y), v1 = __int_as_float(eb.y);
            const float v2 = __int_as_float(ec.y), v3 = __int_as_float(ed.y);
            acc.x += v0 * (float)h0.x; acc.y += v0 * (float)h0.y;
            acc.x += v1 * (float)h1.x; acc.y += v1 * (float)h1.y;
            acc.x += v2 * (float)h2.x; acc.y += v2 * (float)h2.y;
            acc.x += v3 * (float)h3.x; acc.y += v3 * (float)h3.y;
        }
        for (; j < e1; j++) {
            const int2 e = ebuf[j];
            const float v = __int_as_float(e.y);
            const half2v hv = hp[(size_t)(e.x >> 6) * 64 + lane];
            acc.x += v * (float)hv.x; acc.y += v * (float)hv.y;
        }
        for (int t2 = cl; t2 < total; t2++) {     // LDS overflow tail (rare)
            const int2 e = sedge[beg + t2];
            if ((e.x & 63) == n) {
                const float v = __int_as_float(e.y);
                const half2v hv = hp[(size_t)(e.x >> 6) * 64 + lane];
                acc.x += v * (float)hv.x; acc.y += v * (float)hv.y;
            }
        }
        // non-temporal RMW of out (stream-once; don't evict h from LLC)
        union { double d; float2 f; } bv, rv;
        const double* op = (const double*)out + (size_t)node * 64 + lane;
        bv.d = __builtin_nontemporal_load(op);
        rv.f.x = tanhf(acc.x + bv.f.x);
        rv.f.y = tanhf(acc.y + bv.f.y);
        __builtin_nontemporal_store(rv.d, (double*)out + (size_t)node * 64 + lane);
    }
}

// ---------------- fallback (atomic) path --------------------------------

__global__ __launch_bounds__(256)
void edge_scatter(const int* __restrict__ esrc, const int* __restrict__ edst,
                  const float* __restrict__ vals, const _Float16* __restrict__ h,
                  float* __restrict__ out, int E) {
    const int gtid = blockIdx.x * blockDim.x + threadIdx.x;
    const int wave = gtid >> 6;
    const int lane = threadIdx.x & 63;
    const int nw = (gridDim.x * blockDim.x) >> 6;
    for (int e = wave; e < E; e += nw) {
        const int s = esrc[e];
        const int d = edst[e];
        const float v = vals[e];
        const half2v hv = *(const half2v*)(h + (size_t)s * 128 + lane * 2);
        float* op = out + (size_t)d * 128 + lane * 2;
        atomicAdd(op, v * (float)hv.x);
        atomicAdd(op + 1, v * (float)hv.y);
    }
}

__global__ __launch_bounds__(256)
void tanh_kernel(float* __restrict__ out, int n4) {
    const int i = blockIdx.x * blockDim.x + threadIdx.x;
    if (i < n4) {
        float4 v = ((float4*)out)[i];
        v.x = tanhf(v.x);
        v.y = tanhf(v.y);
        v.z = tanhf(v.z);
        v.w = tanhf(v.w);
        ((float4*)out)[i] = v;
    }
}

static inline size_t align64(size_t x) { return (x + 63) & ~(size_t)63; }

extern "C" void kernel_launch(void* const* d_in, const int* in_sizes, int n_in,
                              void* d_out, int out_size, void* d_ws, size_t ws_size,
                              hipStream_t stream) {
    const float* seq    = (const float*)d_in[0];
    const int*   esrc   = (const int*)  d_in[1];
    const int*   edst   = (const int*)  d_in[2];
    const float* vals   = (const float*)d_in[3];
    const float* w_fc   = (const float*)d_in[4];
    const float* w_proj = (const float*)d_in[5];
    const float* b_proj = (const float*)d_in[6];
    const float* bias   = (const float*)d_in[7];
    float* out = (float*)d_out;

    const int N = in_sizes[0] / 128;
    const int E = in_sizes[1];
    const int NB = (N + 63) >> 6;
    const int L  = NB * PG;                       // histogram entries
    const int S  = (E + PG - 1) / PG;             // slice size
    const int nsb = (L + 1023) / 1024;            // scan blocks

    // workspace layout
    char* ws = (char*)d_ws;
    const size_t o_h     = 0;                                      // N*128 fp16
    const size_t o_whif  = align64(o_h    + (size_t)N * 128 * 2);
    const size_t o_wlof  = align64(o_whif + 32768);
    const size_t o_whip  = align64(o_wlof + 32768);
    const size_t o_wlop  = align64(o_whip + 32768);
    const size_t o_hc    = align64(o_wlop + 32768);                // L i32 (hist)
    const size_t o_pos   = align64(o_hc   + (size_t)L * 4);        // L i32 (scan)
    const size_t o_bs    = align64(o_pos  + (size_t)L * 4);        // NB+1 i32
    const size_t o_bsum  = align64(o_bs   + (size_t)(NB + 1) * 4); // 256 i32
    const size_t o_ebs   = align64(o_bsum + 1024);                 // 256 i32
    const size_t o_sed   = align64(o_ebs  + 1024);                 // E int2
    const size_t need    = o_sed + (size_t)E * 8;

    _Float16* h   = (_Float16*)(ws + o_h);
    short* whi_fc = (short*)(ws + o_whif);
    short* wlo_fc = (short*)(ws + o_wlof);
    short* whi_pj = (short*)(ws + o_whip);
    short* wlo_pj = (short*)(ws + o_wlop);
    int*   hcnt   = (int*)  (ws + o_hc);
    int*   pos    = (int*)  (ws + o_pos);
    int*   bstart = (int*)  (ws + o_bs);
    int*   bsum   = (int*)  (ws + o_bsum);
    int*   ebsum  = (int*)  (ws + o_ebs);
    int2*  sedge  = (int2*) (ws + o_sed);

    const int mm_blocks = (N + 63) / 64;

    wconv_kernel<<<16, 256, 0, stream>>>(w_fc,   whi_fc, wlo_fc);
    wconv_kernel<<<16, 256, 0, stream>>>(w_proj, whi_pj, wlo_pj);
    mm_mfma_kernel<<<mm_blocks, 256, 0, stream>>>(seq, whi_fc, wlo_fc, nullptr, nullptr, nullptr, h, N, 0);
    mm_mfma_kernel<<<mm_blocks, 256, 0, stream>>>(seq, whi_pj, wlo_pj, b_proj, bias, out, nullptr, N, 1);

    if (ws_size >= need && NB <= NBMAX && nsb <= 256) {
        phist_kernel<<<PG, 256, 0, stream>>>(edst, hcnt, E, S, NB);
        pscan1_kernel<<<nsb, 256, 0, stream>>>(hcnt, pos, bsum, L);
        pscan2_kernel<<<1, 256, 0, stream>>>(bsum, ebsum, nsb);
        paddback_kernel<<<nsb, 256, 0, stream>>>(pos, ebsum, bstart, L, NB, E);
        pscatter_kernel<<<PG, 256, 0, stream>>>(esrc, edst, vals, pos, sedge, E, S, NB);
        aggregate_sorted<<<NB, 256, 0, stream>>>(bstart, sedge, h, out, N);
    } else {
        edge_scatter<<<8192, 256, 0, stream>>>(esrc, edst, vals, h, out, E);
        const int n4 = (N * 128) / 4;
        tanh_kernel<<<(n4 + 255) / 256, 256, 0, stream>>>(out, n4);
    }
}

// Round 2
// 324.671 us; speedup vs baseline: 1.2487x; 1.0741x over previous
//
#include <hip/hip_runtime.h>
#include <math.h>

// ---------------------------------------------------------------------------
// GCN layer: out = tanh( scatter_add(adj_vals * h[src] -> dst)
//                        + seq @ w_proj + b_proj + bias ),   h = seq @ w_fc
// N=100000, E=1600000, D=128, fp32.
// R7 -> R8:
//  * agg was part latency-bound (4 loads in flight) + ~55 VALU-cy/edge
//    (64-bit addr arith). Inner loop unrolled 8-deep with 32-bit byte
//    offsets (src<<8 + lane*4 on SGPR base).
//  * PG 128->256: phist/pscatter were using half the GPU (128 blocks).
//    pscan1/paddback now cover 2048 entries/block so nsb stays <=256.
//  * two wconv launches fused into one (grid 32).
// ---------------------------------------------------------------------------

typedef __attribute__((ext_vector_type(8))) short short8;
typedef __attribute__((ext_vector_type(4))) float float4v;
typedef __attribute__((ext_vector_type(2))) _Float16 half2v;

#define PG 256          // partition blocks (slices)
#define NBMAX 2048      // max buckets (64 nodes each)

static __device__ __forceinline__ short f2bf(float x) {
    unsigned u = __float_as_uint(x);
    unsigned r = (u + 0x7fffu + ((u >> 16) & 1u)) >> 16;   // RNE
    return (short)r;
}
static __device__ __forceinline__ float bf2f(short h) {
    return __uint_as_float(((unsigned)(unsigned short)h) << 16);
}

// ---------------- W pre-conversion: w[k][c] fp32 -> whi/wlo[c][k] bf16 ------
// One launch converts both weight matrices (blocks 0-15: w_fc, 16-31: w_proj).
__global__ __launch_bounds__(256)
void wconv_kernel(const float* __restrict__ wa, const float* __restrict__ wb,
                  short* __restrict__ whia, short* __restrict__ wloa,
                  short* __restrict__ whib, short* __restrict__ wlob) {
    const int bb = blockIdx.x;
    const float* w  = (bb < 16) ? wa   : wb;
    short* whi      = (bb < 16) ? whia : whib;
    short* wlo      = (bb < 16) ? wloa : wlob;
    const int i = (bb & 15) * 256 + threadIdx.x;    // 4096 float4s
    const float4 v = ((const float4*)w)[i];
    const int k = i >> 5;
    const int c4 = (i & 31) * 4;
    float xs[4] = {v.x, v.y, v.z, v.w};
    #pragma unroll
    for (int j = 0; j < 4; j++) {
        const short hi = f2bf(xs[j]);
        const short lo = f2bf(xs[j] - bf2f(hi));
        whi[(c4 + j) * 128 + k] = hi;
        wlo[(c4 + j) * 128 + k] = lo;
    }
}

// ---------------- MFMA matmul: out[N x 128] = seq[N x 128] @ w[128 x 128] ---
// A*B ~= Ah*Bh + Ah*Bl + Al*Bh (split bf16, rel err ~1e-5).
// out16 != nullptr -> store fp16 (h path); else fp32 + bias (proj path).
#define KP 136

__global__ __launch_bounds__(256, 2)
void mm_mfma_kernel(const float* __restrict__ seq, const short* __restrict__ whi,
                    const short* __restrict__ wlo,
                    const float* __restrict__ b0p, const float* __restrict__ b1p,
                    float* __restrict__ out, _Float16* __restrict__ out16,
                    int N, int add_bias) {
    __shared__ short wt_hi[128 * KP];
    __shared__ short wt_lo[128 * KP];

    const int tid = threadIdx.x;
    for (int i = tid; i < 2048; i += 256) {
        const int row = i >> 4;
        const int k8  = (i & 15) * 8;
        *(float4*)&wt_hi[row * KP + k8] = ((const float4*)whi)[i];
        *(float4*)&wt_lo[row * KP + k8] = ((const float4*)wlo)[i];
    }
    __syncthreads();

    const int wave = tid >> 6;
    const int lane = tid & 63;
    const int q = lane >> 4;
    const int c = lane & 15;
    const int R = blockIdx.x * 64 + wave * 16;
    const int rowL = (R + c < N) ? (R + c) : (N - 1);

    float4v acc[8];
    #pragma unroll
    for (int ct = 0; ct < 8; ct++) acc[ct] = (float4v){0.f, 0.f, 0.f, 0.f};

    #pragma unroll
    for (int t = 0; t < 4; t++) {
        const int kk = t * 32 + q * 8;
        const float4 a0 = *(const float4*)&seq[(size_t)rowL * 128 + kk];
        const float4 a1 = *(const float4*)&seq[(size_t)rowL * 128 + kk + 4];
        float xs[8] = {a0.x, a0.y, a0.z, a0.w, a1.x, a1.y, a1.z, a1.w};
        union { short s[8]; short8 v; } ahi, alo;
        #pragma unroll
        for (int j = 0; j < 8; j++) {
            const short hi = f2bf(xs[j]);
            ahi.s[j] = hi;
            alo.s[j] = f2bf(xs[j] - bf2f(hi));
        }
        #pragma unroll
        for (int ct = 0; ct < 8; ct++) {
            const int n = ct * 16 + c;
            const short8 bhi = *(const short8*)&wt_hi[n * KP + kk];
            const short8 blo = *(const short8*)&wt_lo[n * KP + kk];
            acc[ct] = __builtin_amdgcn_mfma_f32_16x16x32_bf16(ahi.v, bhi, acc[ct], 0, 0, 0);
            acc[ct] = __builtin_amdgcn_mfma_f32_16x16x32_bf16(ahi.v, blo, acc[ct], 0, 0, 0);
            acc[ct] = __builtin_amdgcn_mfma_f32_16x16x32_bf16(alo.v, bhi, acc[ct], 0, 0, 0);
        }
    }

    if (out16) {
        #pragma unroll
        for (int ct = 0; ct < 8; ct++) {
            const int col = ct * 16 + c;
            #pragma unroll
            for (int r = 0; r < 4; r++) {
                const int row = R + q * 4 + r;
                if (row < N) out16[(size_t)row * 128 + col] = (_Float16)acc[ct][r];
            }
        }
    } else {
        #pragma unroll
        for (int ct = 0; ct < 8; ct++) {
            const int col = ct * 16 + c;
            float badd = 0.f;
            if (add_bias) badd = b0p[col] + b1p[col];
            #pragma unroll
            for (int r = 0; r < 4; r++) {
                const int row = R + q * 4 + r;
                if (row < N) out[(size_t)row * 128 + col] = acc[ct][r] + badd;
            }
        }
    }
}

// ---------------- atomic-free radix partition (bucket = dst>>6) ------------

// Per-slice LDS histogram -> hcnt[b*PG + g] (bucket-major for the scan).
__global__ __launch_bounds__(256)
void phist_kernel(const int* __restrict__ edst, int* __restrict__ hcnt,
                  int E, int S, int NB) {
    __shared__ int cnt[NBMAX];
    const int g = blockIdx.x;
    const int tid = threadIdx.x;
    for (int b = tid; b < NB; b += 256) cnt[b] = 0;
    __syncthreads();
    const int lo = g * S;
    const int hi = (lo + S < E) ? (lo + S) : E;
    for (int i = lo + tid; i < hi; i += 256)
        atomicAdd(&cnt[edst[i] >> 6], 1);
    __syncthreads();
    for (int b = tid; b < NB; b += 256) hcnt[b * PG + g] = cnt[b];
}

// Exclusive scan over L = NB*PG entries. pscan1: per-block (2048 elems)
// exclusive prefix + block sums.
__global__ __launch_bounds__(256)
void pscan1_kernel(const int* __restrict__ in, int* __restrict__ out,
                   int* __restrict__ bsum, int L) {
    __shared__ int s[256];
    const int t = threadIdx.x;
    const int base = blockIdx.x * 2048 + t * 8;
    int v[8];
    int mysum = 0;
    #pragma unroll
    for (int j = 0; j < 8; j++) {
        v[j] = (base + j < L) ? in[base + j] : 0;
        mysum += v[j];
    }
    s[t] = mysum;
    __syncthreads();
    for (int o = 1; o < 256; o <<= 1) {
        int add = (t >= o) ? s[t - o] : 0;
        __syncthreads();
        s[t] += add;
        __syncthreads();
    }
    int run = s[t] - mysum;
    #pragma unroll
    for (int j = 0; j < 8; j++) {
        if (base + j < L) out[base + j] = run;
        run += v[j];
    }
    if (t == 255) bsum[blockIdx.x] = s[255];
}

// Single block: exclusive scan of nb (<=256) block sums.
__global__ __launch_bounds__(256)
void pscan2_kernel(const int* __restrict__ bsum, int* __restrict__ ebsum, int nb) {
    __shared__ int s[256];
    const int t = threadIdx.x;
    const int v = (t < nb) ? bsum[t] : 0;
    s[t] = v;
    __syncthreads();
    for (int o = 1; o < 256; o <<= 1) {
        int add = (t >= o) ? s[t - o] : 0;
        __syncthreads();
        s[t] += add;
        __syncthreads();
    }
    if (t < nb) ebsum[t] = s[t] - v;
}

// pos[i] += ebsum[block]; also emit bstart[b] = pos[b*PG] and bstart[NB] = E.
__global__ __launch_bounds__(256)
void paddback_kernel(int* __restrict__ pos, const int* __restrict__ ebsum,
                     int* __restrict__ bstart, int L, int NB, int E) {
    const int add = ebsum[blockIdx.x];
    const int base = blockIdx.x * 2048 + threadIdx.x * 8;
    #pragma unroll
    for (int j = 0; j < 8; j++) {
        const int idx = base + j;
        if (idx < L) {
            const int v = pos[idx] + add;
            pos[idx] = v;
            if ((idx & (PG - 1)) == 0) bstart[idx / PG] = v;
        }
    }
    if (blockIdx.x == 0 && threadIdx.x == 0) bstart[NB] = E;
}

// Atomic-free (global) scatter: LDS cursors seeded from pos.
// entry = (src<<6 | dst&63, val) : 8B.
__global__ __launch_bounds__(256)
void pscatter_kernel(const int* __restrict__ esrc, const int* __restrict__ edst,
                     const float* __restrict__ vals, const int* __restrict__ pos,
                     int2* __restrict__ sedge, int E, int S, int NB) {
    __shared__ int cur[NBMAX];
    const int g = blockIdx.x;
    const int tid = threadIdx.x;
    for (int b = tid; b < NB; b += 256) cur[b] = pos[b * PG + g];
    __syncthreads();
    const int lo = g * S;
    const int hi = (lo + S < E) ? (lo + S) : E;
    for (int i = lo + tid; i < hi; i += 256) {
        const int d = edst[i];
        const int p = atomicAdd(&cur[d >> 6], 1);
        sedge[p] = make_int2((esrc[i] << 6) | (d & 63), __float_as_int(vals[i]));
    }
}

// One block (256 thr) per 64-node bucket. Counting-sort edges by node into
// LDS (16KB), then each wave aggregates 16 nodes with REGISTER accumulation:
// coalesced 256B fp16 h-row gathers (8-deep, 32-bit offsets), fused tanh.
// out RMW is non-temporal (one-shot stream; keep h resident in LLC).
#define CAP 2048

__global__ __launch_bounds__(256, 8)
void aggregate_sorted(const int* __restrict__ bstart, const int2* __restrict__ sedge,
                      const _Float16* __restrict__ h, float* __restrict__ out, int N) {
    __shared__ int2 ebuf[CAP];
    __shared__ int cnt[64], sc[64], off[65], cur[64];
    const int b = blockIdx.x;
    const int tid = threadIdx.x;
    const int beg = bstart[b];
    const int total = bstart[b + 1] - beg;
    const int cl = total < CAP ? total : CAP;     // edges sorted in LDS

    if (tid < 64) cnt[tid] = 0;
    __syncthreads();
    for (int i = tid; i < cl; i += 256)
        atomicAdd(&cnt[sedge[beg + i].x & 63], 1);
    __syncthreads();
    if (tid < 64) sc[tid] = cnt[tid];
    __syncthreads();
    for (int o = 1; o < 64; o <<= 1) {
        int add = (tid < 64 && tid >= o) ? sc[tid - o] : 0;
        __syncthreads();
        if (tid < 64) sc[tid] += add;
        __syncthreads();
    }
    if (tid < 64) { off[tid] = sc[tid] - cnt[tid]; cur[tid] = sc[tid] - cnt[tid]; }
    if (tid == 63) off[64] = sc[63];
    __syncthreads();
    for (int i = tid; i < cl; i += 256) {
        const int2 e = sedge[beg + i];
        const int p = atomicAdd(&cur[e.x & 63], 1);
        ebuf[p] = e;
    }
    __syncthreads();

    const int wave = tid >> 6;
    const int lane = tid & 63;
    const char* hb = (const char*)h;
    const int loff = lane << 2;                   // 4B per lane (half2)

    for (int n = wave * 16; n < wave * 16 + 16; n++) {
        const int node = b * 64 + n;
        if (node >= N) break;
        float2 acc = make_float2(0.f, 0.f);
        const int e0 = off[n], e1 = off[n + 1];
        int j = e0;
        for (; j + 8 <= e1; j += 8) {
            const int2 e0v = ebuf[j],     e1v = ebuf[j + 1];
            const int2 e2v = ebuf[j + 2], e3v = ebuf[j + 3];
            const int2 e4v = ebuf[j + 4], e5v = ebuf[j + 5];
            const int2 e6v = ebuf[j + 6], e7v = ebuf[j + 7];
            const half2v h0 = *(const half2v*)(hb + ((((unsigned)e0v.x >> 6) << 8) + loff));
            const half2v h1 = *(const half2v*)(hb + ((((unsigned)e1v.x >> 6) << 8) + loff));
            const half2v h2 = *(const half2v*)(hb + ((((unsigned)e2v.x >> 6) << 8) + loff));
            const half2v h3 = *(const half2v*)(hb + ((((unsigned)e3v.x >> 6) << 8) + loff));
            const half2v h4 = *(const half2v*)(hb + ((((unsigned)e4v.x >> 6) << 8) + loff));
            const half2v h5 = *(const half2v*)(hb + ((((unsigned)e5v.x >> 6) << 8) + loff));
            const half2v h6 = *(const half2v*)(hb + ((((unsigned)e6v.x >> 6) << 8) + loff));
            const half2v h7 = *(const half2v*)(hb + ((((unsigned)e7v.x >> 6) << 8) + loff));
            const float v0 = __int_as_float(e0v.y), v1 = __int_as_float(e1v.y);
            const float v2 = __int_as_float(e2v.y), v3 = __int_as_float(e3v.y);
            const float v4 = __int_as_float(e4v.y), v5 = __int_as_float(e5v.y);
            const float v6 = __int_as_float(e6v.y), v7 = __int_as_float(e7v.y);
            acc.x += v0 * (float)h0.x; acc.y += v0 * (float)h0.y;
            acc.x += v1 * (float)h1.x; acc.y += v1 * (float)h1.y;
            acc.x += v2 * (float)h2.x; acc.y += v2 * (float)h2.y;
            acc.x += v3 * (float)h3.x; acc.y += v3 * (float)h3.y;
            acc.x += v4 * (float)h4.x; acc.y += v4 * (float)h4.y;
            acc.x += v5 * (float)h5.x; acc.y += v5 * (float)h5.y;
            acc.x += v6 * (float)h6.x; acc.y += v6 * (float)h6.y;
            acc.x += v7 * (float)h7.x; acc.y += v7 * (float)h7.y;
        }
        for (; j + 4 <= e1; j += 4) {
            const int2 ea = ebuf[j], eb = ebuf[j + 1], ec = ebuf[j + 2], ed = ebuf[j + 3];
            const half2v h0 = *(const half2v*)(hb + ((((unsigned)ea.x >> 6) << 8) + loff));
            const half2v h1 = *(const half2v*)(hb + ((((unsigned)eb.x >> 6) << 8) + loff));
            const half2v h2 = *(const half2v*)(hb + ((((unsigned)ec.x >> 6) << 8) + loff));
            const half2v h3 = *(const half2v*)(hb + ((((unsigned)ed.x >> 6) << 8) + loff));
            const float v0 = __int_as_float(ea.y), v1 = __int_as_float(eb.y);
            const float v2 = __int_as_float(ec.y), v3 = __int_as_float(ed.y);
            acc.x += v0 * (float)h0.x; acc.y += v0 * (float)h0.y;
            acc.x += v1 * (float)h1.x; acc.y += v1 * (float)h1.y;
            acc.x += v2 * (float)h2.x; acc.y += v2 * (float)h2.y;
            acc.x += v3 * (float)h3.x; acc.y += v3 * (float)h3.y;
        }
        for (; j < e1; j++) {
            const int2 e = ebuf[j];
            const float v = __int_as_float(e.y);
            const half2v hv = *(const half2v*)(hb + ((((unsigned)e.x >> 6) << 8) + loff));
            acc.x += v * (float)hv.x; acc.y += v * (float)hv.y;
        }
        for (int t2 = cl; t2 < total; t2++) {     // LDS overflow tail (rare)
            const int2 e = sedge[beg + t2];
            if ((e.x & 63) == n) {
                const float v = __int_as_float(e.y);
                const half2v hv = *(const half2v*)(hb + ((((unsigned)e.x >> 6) << 8) + loff));
                acc.x += v * (float)hv.x; acc.y += v * (float)hv.y;
            }
        }
        // non-temporal RMW of out (stream-once; don't evict h from LLC)
        union { double d; float2 f; } bv, rv;
        const double* op = (const double*)out + (size_t)node * 64 + lane;
        bv.d = __builtin_nontemporal_load(op);
        rv.f.x = tanhf(acc.x + bv.f.x);
        rv.f.y = tanhf(acc.y + bv.f.y);
        __builtin_nontemporal_store(rv.d, (double*)out + (size_t)node * 64 + lane);
    }
}

// ---------------- fallback (atomic) path --------------------------------

__global__ __launch_bounds__(256)
void edge_scatter(const int* __restrict__ esrc, const int* __restrict__ edst,
                  const float* __restrict__ vals, const _Float16* __restrict__ h,
                  float* __restrict__ out, int E) {
    const int gtid = blockIdx.x * blockDim.x + threadIdx.x;
    const int wave = gtid >> 6;
    const int lane = threadIdx.x & 63;
    const int nw = (gridDim.x * blockDim.x) >> 6;
    for (int e = wave; e < E; e += nw) {
        const int s = esrc[e];
        const int d = edst[e];
        const float v = vals[e];
        const half2v hv = *(const half2v*)(h + (size_t)s * 128 + lane * 2);
        float* op = out + (size_t)d * 128 + lane * 2;
        atomicAdd(op, v * (float)hv.x);
        atomicAdd(op + 1, v * (float)hv.y);
    }
}

__global__ __launch_bounds__(256)
void tanh_kernel(float* __restrict__ out, int n4) {
    const int i = blockIdx.x * blockDim.x + threadIdx.x;
    if (i < n4) {
        float4 v = ((float4*)out)[i];
        v.x = tanhf(v.x);
        v.y = tanhf(v.y);
        v.z = tanhf(v.z);
        v.w = tanhf(v.w);
        ((float4*)out)[i] = v;
    }
}

static inline size_t align64(size_t x) { return (x + 63) & ~(size_t)63; }

extern "C" void kernel_launch(void* const* d_in, const int* in_sizes, int n_in,
                              void* d_out, int out_size, void* d_ws, size_t ws_size,
                              hipStream_t stream) {
    const float* seq    = (const float*)d_in[0];
    const int*   esrc   = (const int*)  d_in[1];
    const int*   edst   = (const int*)  d_in[2];
    const float* vals   = (const float*)d_in[3];
    const float* w_fc   = (const float*)d_in[4];
    const float* w_proj = (const float*)d_in[5];
    const float* b_proj = (const float*)d_in[6];
    const float* bias   = (const float*)d_in[7];
    float* out = (float*)d_out;

    const int N = in_sizes[0] / 128;
    const int E = in_sizes[1];
    const int NB = (N + 63) >> 6;
    const int L  = NB * PG;                       // histogram entries
    const int S  = (E + PG - 1) / PG;             // slice size
    const int nsb = (L + 2047) / 2048;            // scan blocks

    // workspace layout
    char* ws = (char*)d_ws;
    const size_t o_h     = 0;                                      // N*128 fp16
    const size_t o_whif  = align64(o_h    + (size_t)N * 128 * 2);
    const size_t o_wlof  = align64(o_whif + 32768);
    const size_t o_whip  = align64(o_wlof + 32768);
    const size_t o_wlop  = align64(o_whip + 32768);
    const size_t o_hc    = align64(o_wlop + 32768);                // L i32 (hist)
    const size_t o_pos   = align64(o_hc   + (size_t)L * 4);        // L i32 (scan)
    const size_t o_bs    = align64(o_pos  + (size_t)L * 4);        // NB+1 i32
    const size_t o_bsum  = align64(o_bs   + (size_t)(NB + 1) * 4); // 256 i32
    const size_t o_ebs   = align64(o_bsum + 1024);                 // 256 i32
    const size_t o_sed   = align64(o_ebs  + 1024);                 // E int2
    const size_t need    = o_sed + (size_t)E * 8;

    _Float16* h   = (_Float16*)(ws + o_h);
    short* whi_fc = (short*)(ws + o_whif);
    short* wlo_fc = (short*)(ws + o_wlof);
    short* whi_pj = (short*)(ws + o_whip);
    short* wlo_pj = (short*)(ws + o_wlop);
    int*   hcnt   = (int*)  (ws + o_hc);
    int*   pos    = (int*)  (ws + o_pos);
    int*   bstart = (int*)  (ws + o_bs);
    int*   bsum   = (int*)  (ws + o_bsum);
    int*   ebsum  = (int*)  (ws + o_ebs);
    int2*  sedge  = (int2*) (ws + o_sed);

    const int mm_blocks = (N + 63) / 64;

    wconv_kernel<<<32, 256, 0, stream>>>(w_fc, w_proj, whi_fc, wlo_fc, whi_pj, wlo_pj);
    mm_mfma_kernel<<<mm_blocks, 256, 0, stream>>>(seq, whi_fc, wlo_fc, nullptr, nullptr, nullptr, h, N, 0);
    mm_mfma_kernel<<<mm_blocks, 256, 0, stream>>>(seq, whi_pj, wlo_pj, b_proj, bias, out, nullptr, N, 1);

    if (ws_size >= need && NB <= NBMAX && nsb <= 256) {
        phist_kernel<<<PG, 256, 0, stream>>>(edst, hcnt, E, S, NB);
        pscan1_kernel<<<nsb, 256, 0, stream>>>(hcnt, pos, bsum, L);
        pscan2_kernel<<<1, 256, 0, stream>>>(bsum, ebsum, nsb);
        paddback_kernel<<<nsb, 256, 0, stream>>>(pos, ebsum, bstart, L, NB, E);
        pscatter_kernel<<<PG, 256, 0, stream>>>(esrc, edst, vals, pos, sedge, E, S, NB);
        aggregate_sorted<<<NB, 256, 0, stream>>>(bstart, sedge, h, out, N);
    } else {
        edge_scatter<<<8192, 256, 0, stream>>>(esrc, edst, vals, h, out, E);
        const int n4 = (N * 128) / 4;
        tanh_kernel<<<(n4 + 255) / 256, 256, 0, stream>>>(out, n4);
    }
}